// Round 7
// baseline (48.855 us; speedup 1.0000x reference)
//
#include <hip/hip_runtime.h>

#define SB 4096
#define BB 16
#define CC 512
#define RPB 4
#define CH 8

struct Small {
  int   fl_old[BB];
  int   fl_new[BB];
  float scale[BB];
  int   flag_u8;
};

// K1: per-batch parallel cumsum (one 256-thread block per batch).
__global__ void __launch_bounds__(256)
k_scan(const float* __restrict__ alphas, const void* __restrict__ mask,
       float* __restrict__ csum, Small* sm) {
  int b = blockIdx.x;
  int t = threadIdx.x;
  __shared__ int s_flag;
  if (t == 0) s_flag = 0;
  __syncthreads();
  const unsigned* mw_ = (const unsigned*)mask;
  unsigned bad = 0;
  for (int i = t; i < 16384; i += 256) bad |= (mw_[i] > 1u) ? 1u : 0u;
  if (bad) atomicOr(&s_flag, 1);
  __syncthreads();
  int flag = s_flag;
  if (b == 0 && t == 0) sm->flag_u8 = flag;

  int lane = t & 63, wid = t >> 6;
  int base = t * 16;
  const float* ab = alphas + b * SB + base;
  float av[16];
#pragma unroll
  for (int k = 0; k < 16; k += 4) {
    float4 v = *(const float4*)(ab + k);
    av[k] = v.x; av[k + 1] = v.y; av[k + 2] = v.z; av[k + 3] = v.w;
  }
  if (flag) {
    const unsigned char* mb = (const unsigned char*)mask + b * SB + base;
    uint4 mv = *(const uint4*)mb;
    unsigned mw[4] = {mv.x, mv.y, mv.z, mv.w};
#pragma unroll
    for (int k = 0; k < 16; ++k)
      if ((mw[k >> 2] >> ((k & 3) * 8)) & 0xFFu) av[k] = 0.f;
  } else {
    const int* mi = (const int*)mask + b * SB + base;
#pragma unroll
    for (int k = 0; k < 16; ++k)
      if (mi[k]) av[k] = 0.f;
  }
  float s = 0.f;
#pragma unroll
  for (int k = 0; k < 16; ++k) s += av[k];
  float si = s;
#pragma unroll
  for (int off = 1; off < 64; off <<= 1) {
    float v = __shfl_up(si, off);
    if (lane >= off) si += v;
  }
  __shared__ float wsum[4];
  if (lane == 63) wsum[wid] = si;
  __syncthreads();
  float woff = 0.f;
  for (int w = 0; w < wid; ++w) woff += wsum[w];
  float c = woff + (si - s);  // exclusive prefix
  float* cb = csum + b * SB + base;
#pragma unroll
  for (int k = 0; k < 16; ++k) { c += av[k]; cb[k] = c; }
  if (t == 255) {
    float total = woff + si;
    sm->fl_old[b] = (int)floorf(total);
  }
}

// K2: weights {lw, rw}, fire-position scatter S[b][r]=i (plain stores),
// tail reduction -> scale/fl_new/feat_lengths out.
__global__ void __launch_bounds__(256)
k_weights(const float* __restrict__ alphas, const void* __restrict__ mask,
          const float* __restrict__ csum, Small* sm,
          float2* __restrict__ wlr, int* __restrict__ S,
          float* __restrict__ out1, int T) {
  int b = blockIdx.x;
  int t = threadIdx.x;
  int flag = sm->flag_u8;
  int T0 = sm->fl_old[0];
#pragma unroll
  for (int j = 1; j < BB; ++j) T0 = max(T0, sm->fl_old[j]);
  int fl = sm->fl_old[b];
  int base = t * 16;
  int gbase = b * SB + base;

  float cs[16];
#pragma unroll
  for (int k = 0; k < 16; k += 4) {
    float4 v = *(const float4*)(csum + gbase + k);
    cs[k] = v.x; cs[k + 1] = v.y; cs[k + 2] = v.z; cs[k + 3] = v.w;
  }
  float cprev = (base == 0) ? 0.f : csum[gbase - 1];
  float av[16];
#pragma unroll
  for (int k = 0; k < 16; k += 4) {
    float4 v = *(const float4*)(alphas + gbase + k);
    av[k] = v.x; av[k + 1] = v.y; av[k + 2] = v.z; av[k + 3] = v.w;
  }
  unsigned mbits = 0;
  if (flag) {
    const unsigned char* mb = (const unsigned char*)mask + gbase;
    uint4 mv = *(const uint4*)mb;
    unsigned mw[4] = {mv.x, mv.y, mv.z, mv.w};
#pragma unroll
    for (int k = 0; k < 16; ++k)
      if ((mw[k >> 2] >> ((k & 3) * 8)) & 0xFFu) { av[k] = 0.f; mbits |= 1u << k; }
  } else {
    const int* mi = (const int*)mask + gbase;
#pragma unroll
    for (int k = 0; k < 16; ++k)
      if (mi[k]) { av[k] = 0.f; mbits |= 1u << k; }
  }

  int lmax = -1;
#pragma unroll
  for (int k = 0; k < 16; ++k) if (!((mbits >> k) & 1u)) lmax = base + k;

  float tc = 0.f;
  float2 w2[16];
  int   rr[16];
  unsigned fbits = 0;
  int p = (base == 0) ? 0 : min((int)rintf(cprev), T0);
#pragma unroll
  for (int k = 0; k < 16; ++k) {
    int r = min((int)rintf(cs[k]), T0);
    int fire = r - p;                       // in {0,1} for alphas < 1
    float rwv = (fire > 0) ? (cs[k] - (float)r) : 0.f;
    float lwv = av[k] - rwv;
    w2[k] = make_float2(lwv, rwv);
    rr[k] = r;
    if (fire > 0) fbits |= 1u << k;
    tc += ((r == fl) ? rwv : 0.f) + ((p == fl) ? lwv : 0.f);
    p = r;
  }
#pragma unroll
  for (int k = 0; k < 16; k += 2) {
    float4 st = make_float4(w2[k].x, w2[k].y, w2[k + 1].x, w2[k + 1].y);
    *(float4*)(wlr + gbase + k) = st;
  }

  for (int off = 32; off; off >>= 1) {
    lmax = max(lmax, __shfl_down(lmax, off));
    tc += __shfl_down(tc, off);
  }
  __shared__ int   redl[4];
  __shared__ float redt[4];
  int wid = t >> 6;
  if ((t & 63) == 0) { redl[wid] = lmax; redt[wid] = tc; }
  __syncthreads();
  int llast = max(max(redl[0], redl[1]), max(redl[2], redl[3]));

  int* Sb = S + b * (T + 2);
  for (int j = t; j < T + 2; j += 256) Sb[j] = (j == 0) ? 0 : llast;
  __syncthreads();
#pragma unroll
  for (int k = 0; k < 16; ++k)
    if ((fbits >> k) & 1u) Sb[rr[k]] = base + k;

  if (t == 0) {
    float tail = redt[0] + redt[1] + redt[2] + redt[3];
    int e = (tail >= 0.5f) ? 1 : 0;
    sm->scale[b] = e ? (1.0f / tail) : 1.0f;
    int fln = fl + e;
    sm->fl_new[b] = fln;
    out1[b] = (float)max(fln, 1);
  }
}

// K3: gather, RPB consecutive rows per block, CH-deep load chunks.
// NO XCD swizzle: default round-robin dispatch balances per-XCD work
// (chunked swizzle gave each XCD 2 whole batches; len_b varies 2x -> 26% imbalance).
__global__ void __launch_bounds__(128)
k_gather(const float* __restrict__ src, const float2* __restrict__ wlr,
         const int* __restrict__ S, const Small* __restrict__ sm,
         float* __restrict__ out, int T, int nwgx) {
  int wg = blockIdx.x;
  int b  = wg / nwgx;
  int t0 = (wg - b * nwgx) * RPB;

  int tid = threadIdx.x;
  int fln = sm->fl_new[b];
  int flo = sm->fl_old[b];
  float sc = sm->scale[b];
  float* outb = out + ((size_t)b * T + t0) * CC;

  int nrows = T - t0; if (nrows > RPB) nrows = RPB;
  int nact = fln - t0; if (nact > RPB) nact = RPB; if (nact < 0) nact = 0;
  for (int j = nact; j < nrows; ++j)
    ((float4*)(outb + (size_t)j * CC))[tid] = make_float4(0.f, 0.f, 0.f, 0.f);
  if (nact <= 0) return;

  const int* Sb = S + b * (T + 2);
  int sarr[RPB + 1];
#pragma unroll
  for (int j = 0; j <= RPB; ++j) sarr[j] = (j <= nact) ? Sb[t0 + j] : 0x7FFFFFFF;

  int start = sarr[0];
  int end   = sarr[nact];
  const float* srcb = src + (size_t)b * SB * CC;
  const float2* wb  = wlr + b * SB;

  float4 acc[RPB];
#pragma unroll
  for (int j = 0; j < RPB; ++j) acc[j] = make_float4(0.f, 0.f, 0.f, 0.f);

  for (int c = start; c <= end; c += CH) {
    int nk = end - c + 1; if (nk > CH) nk = CH;
    float2 w2v[CH];
    float4 sv[CH];
#pragma unroll
    for (int k = 0; k < CH; ++k) {
      int i = (k < nk) ? (c + k) : end;
      w2v[k] = wb[i];
      sv[k]  = ((const float4*)(srcb + (size_t)i * CC))[tid];
    }
#pragma unroll
    for (int k = 0; k < CH; ++k) {
      if (k < nk) {
        int i = c + k;
#pragma unroll
        for (int j = 0; j < RPB; ++j) {
          if (j < nact) {
            bool inr = (i >= sarr[j]) && (i <= sarr[j + 1]);
            float w = (i == sarr[j] && (t0 + j) > 0) ? w2v[k].y : w2v[k].x;
            w = inr ? w : 0.f;
            acc[j].x = fmaf(w, sv[k].x, acc[j].x);
            acc[j].y = fmaf(w, sv[k].y, acc[j].y);
            acc[j].z = fmaf(w, sv[k].z, acc[j].z);
            acc[j].w = fmaf(w, sv[k].w, acc[j].w);
          }
        }
      }
    }
  }
#pragma unroll
  for (int j = 0; j < RPB; ++j) {
    if (j < nact) {
      float m = ((t0 + j) == flo) ? sc : 1.0f;
      float4 v = make_float4(acc[j].x * m, acc[j].y * m, acc[j].z * m, acc[j].w * m);
      ((float4*)(outb + (size_t)j * CC))[tid] = v;
    }
  }
}

extern "C" void kernel_launch(void* const* d_in, const int* in_sizes, int n_in,
                              void* d_out, int out_size, void* d_ws, size_t ws_size,
                              hipStream_t stream) {
  const float* src = (const float*)d_in[0];
  const void* mask = d_in[1];
  const float* alphas = (const float*)d_in[2];
  float* out = (float*)d_out;
  char* ws = (char*)d_ws;

  int T = (out_size - BB) / (BB * CC);

  float* csum = (float*)(ws + 0);          // 256 KB
  float2* wlr = (float2*)(ws + 262144);    // 512 KB
  int* S      = (int*)(ws + 786432);       // BB*(T+2)*4
  Small* sm   = (Small*)(ws + 1572864);

  k_scan<<<BB, 256, 0, stream>>>(alphas, mask, csum, sm);
  k_weights<<<BB, 256, 0, stream>>>(alphas, mask, csum, sm, wlr, S,
                                    out + (size_t)BB * T * CC, T);
  int nwgx = (T + RPB - 1) / RPB;
  k_gather<<<BB * nwgx, 128, 0, stream>>>(src, wlr, S, sm, out, T, nwgx);
}

// Round 8
// 38.398 us; speedup vs baseline: 1.2723x; 1.2723x over previous
//
#include <hip/hip_runtime.h>

#define SB 4096
#define BB 16
#define CC 512
#define RPB 4
#define CH 8

struct Small {
  int   fl_old[BB];
  int   fl_new[BB];
  float scale[BB];
};

// K1: per-batch (one 256-thr block per batch): mask-dtype detect (own 4KB
// region), masked cumsum (block scan), csum out, fire-position scatter
// S[b][r]=i (unclipped rint), llast defaults, tail=frac(total) -> scale,
// fl_old/fl_new, feat_lengths out. No cross-block dependencies.
__global__ void __launch_bounds__(256)
k_scan(const float* __restrict__ alphas, const void* __restrict__ mask,
       float* __restrict__ csum, int* __restrict__ S, Small* sm,
       float* __restrict__ out1, int T) {
  int b = blockIdx.x;
  int t = threadIdx.x;

  // mask dtype detect: scan only this batch's own uint8 region (1024 words).
  // uint8-bools: suffix mask makes some word >1 whenever any element of this
  // batch is masked (len<S). int32-bools: words are 0/1, no false positive.
  // len==S => no masked elements under either dtype => flag irrelevant.
  __shared__ int s_flag;
  if (t == 0) s_flag = 0;
  __syncthreads();
  {
    uint4 v = ((const uint4*)mask)[b * 256 + t];
    if ((v.x > 1u) || (v.y > 1u) || (v.z > 1u) || (v.w > 1u)) atomicOr(&s_flag, 1);
  }
  __syncthreads();
  int flag = s_flag;

  int lane = t & 63, wid = t >> 6;
  int base = t * 16;
  const float* ab = alphas + b * SB + base;
  float av[16];
#pragma unroll
  for (int k = 0; k < 16; k += 4) {
    float4 v = *(const float4*)(ab + k);
    av[k] = v.x; av[k + 1] = v.y; av[k + 2] = v.z; av[k + 3] = v.w;
  }
  unsigned mbits = 0;
  if (flag) {
    const unsigned char* mb = (const unsigned char*)mask + b * SB + base;
    uint4 mv = *(const uint4*)mb;
    unsigned mw[4] = {mv.x, mv.y, mv.z, mv.w};
#pragma unroll
    for (int k = 0; k < 16; ++k)
      if ((mw[k >> 2] >> ((k & 3) * 8)) & 0xFFu) { av[k] = 0.f; mbits |= 1u << k; }
  } else {
    const int* mi = (const int*)mask + b * SB + base;
#pragma unroll
    for (int k = 0; k < 16; ++k)
      if (mi[k]) { av[k] = 0.f; mbits |= 1u << k; }
  }

  float s = 0.f;
#pragma unroll
  for (int k = 0; k < 16; ++k) s += av[k];
  float si = s;
#pragma unroll
  for (int off = 1; off < 64; off <<= 1) {
    float v = __shfl_up(si, off);
    if (lane >= off) si += v;
  }
  __shared__ float wsum[4];
  if (lane == 63) wsum[wid] = si;
  __syncthreads();
  float woff = 0.f;
  for (int w = 0; w < wid; ++w) woff += wsum[w];
  float c = woff + (si - s);  // exclusive prefix (fp path differs from csum[base-1])
  float cs[16];
  float* cb = csum + b * SB + base;
#pragma unroll
  for (int k = 0; k < 16; ++k) { c += av[k]; cs[k] = c; cb[k] = c; }

  // exact previous csum (bit-identical): share each thread's final c via LDS
  __shared__ float cfin[256];
  __shared__ int   redl[4];
  int lmax = -1;
#pragma unroll
  for (int k = 0; k < 16; ++k) if (!((mbits >> k) & 1u)) lmax = base + k;
  cfin[t] = cs[15];
  for (int off = 32; off; off >>= 1) lmax = max(lmax, __shfl_down(lmax, off));
  if ((t & 63) == 0) redl[wid] = lmax;
  __syncthreads();
  int llast = max(max(redl[0], redl[1]), max(redl[2], redl[3]));
  float prevc = (t == 0) ? 0.f : cfin[t - 1];

  // init S defaults, then scatter fire positions (unclipped)
  int* Sb = S + b * (T + 3);
  for (int j = t; j < T + 3; j += 256) Sb[j] = (j == 0) ? 0 : llast;
  __syncthreads();
  int p = (int)rintf(prevc);
#pragma unroll
  for (int k = 0; k < 16; ++k) {
    int r = (int)rintf(cs[k]);
    if (r != p && r < T + 3) Sb[r] = base + k;
    p = r;
  }

  if (t == 255) {
    float total = woff + si;
    float fl = floorf(total);
    float frac = total - fl;          // == tail_weights by mass conservation
    int e = (frac >= 0.5f) ? 1 : 0;
    int fli = (int)fl;
    sm->fl_old[b] = fli;
    sm->scale[b] = e ? (1.0f / frac) : 1.0f;
    int fln = fli + e;
    sm->fl_new[b] = fln;
    out1[b] = (float)max(fln, 1);
  }
}

// K2: gather, RPB consecutive rows per block, CH-deep load chunks.
// Weights recomputed on the fly from csum:
//   middle elem:        w = csum_i - csum_{i-1}   (masked alpha)
//   start (firer into t, t>0): w = csum_i - t              (right_weight)
//   end (firer into t+1):      w = (t+1) - csum_{i-1}      (left_weight)
//   end (non-firer, llast default): w = middle formula
__global__ void __launch_bounds__(128)
k_gather(const float* __restrict__ src, const float* __restrict__ csum,
         const int* __restrict__ S, const Small* __restrict__ sm,
         float* __restrict__ out, int T, int nwgx) {
  int wg = blockIdx.x;
  int b  = wg / nwgx;
  int t0 = (wg - b * nwgx) * RPB;

  int tid = threadIdx.x;
  int fln = sm->fl_new[b];
  int flo = sm->fl_old[b];
  float sc = sm->scale[b];
  float* outb = out + ((size_t)b * T + t0) * CC;

  int nrows = T - t0; if (nrows > RPB) nrows = RPB;
  int nact = fln - t0; if (nact > RPB) nact = RPB; if (nact < 0) nact = 0;
  for (int j = nact; j < nrows; ++j)
    ((float4*)(outb + (size_t)j * CC))[tid] = make_float4(0.f, 0.f, 0.f, 0.f);
  if (nact <= 0) return;

  const int* Sb = S + b * (T + 3);
  int sarr[RPB + 1];
#pragma unroll
  for (int j = 0; j <= RPB; ++j) sarr[j] = (j <= nact) ? Sb[t0 + j] : 0x7FFFFFFF;

  int start = sarr[0];
  int end   = sarr[nact];
  const float* srcb = src + (size_t)b * SB * CC;
  const float* cb   = csum + b * SB;

  float4 acc[RPB];
#pragma unroll
  for (int j = 0; j < RPB; ++j) acc[j] = make_float4(0.f, 0.f, 0.f, 0.f);

  for (int c = start; c <= end; c += CH) {
    int nk = end - c + 1; if (nk > CH) nk = CH;
    float cv[CH], cp[CH];
    float4 sv[CH];
#pragma unroll
    for (int k = 0; k < CH; ++k) {
      int i = (k < nk) ? (c + k) : end;
      cv[k] = cb[i];
      cp[k] = (i > 0) ? cb[i - 1] : 0.f;
      sv[k] = ((const float4*)(srcb + (size_t)i * CC))[tid];
    }
#pragma unroll
    for (int k = 0; k < CH; ++k) {
      if (k < nk) {
        int i = c + k;
        float a = cv[k] - cp[k];
#pragma unroll
        for (int j = 0; j < RPB; ++j) {
          if (j < nact) {
            float tj = (float)(t0 + j);
            float w = a;
            if (i == sarr[j + 1])
              w = (rintf(cv[k]) == tj + 1.0f) ? (tj + 1.0f - cp[k]) : a;
            if (i == sarr[j] && (t0 + j) > 0)
              w = cv[k] - tj;
            bool inr = (i >= sarr[j]) && (i <= sarr[j + 1]);
            w = inr ? w : 0.f;
            acc[j].x = fmaf(w, sv[k].x, acc[j].x);
            acc[j].y = fmaf(w, sv[k].y, acc[j].y);
            acc[j].z = fmaf(w, sv[k].z, acc[j].z);
            acc[j].w = fmaf(w, sv[k].w, acc[j].w);
          }
        }
      }
    }
  }
#pragma unroll
  for (int j = 0; j < RPB; ++j) {
    if (j < nact) {
      float m = ((t0 + j) == flo) ? sc : 1.0f;
      float4 v = make_float4(acc[j].x * m, acc[j].y * m, acc[j].z * m, acc[j].w * m);
      ((float4*)(outb + (size_t)j * CC))[tid] = v;
    }
  }
}

extern "C" void kernel_launch(void* const* d_in, const int* in_sizes, int n_in,
                              void* d_out, int out_size, void* d_ws, size_t ws_size,
                              hipStream_t stream) {
  const float* src = (const float*)d_in[0];
  const void* mask = d_in[1];
  const float* alphas = (const float*)d_in[2];
  float* out = (float*)d_out;
  char* ws = (char*)d_ws;

  int T = (out_size - BB) / (BB * CC);

  float* csum = (float*)(ws + 0);          // 256 KB
  int* S      = (int*)(ws + 262144);       // BB*(T+3)*4
  Small* sm   = (Small*)(ws + 524288);

  k_scan<<<BB, 256, 0, stream>>>(alphas, mask, csum, S, sm,
                                 out + (size_t)BB * T * CC, T);
  int nwgx = (T + RPB - 1) / RPB;
  k_gather<<<BB * nwgx, 128, 0, stream>>>(src, csum, S, sm, out, T, nwgx);
}